// Round 7
// baseline (213.037 us; speedup 1.0000x reference)
//
#include <hip/hip_runtime.h>
#include <cstdint>

#define TICKS   1000
#define KH      7
#define KW      7
#define NTAPS   49
#define OUT_CH  128

#define BUF_ELEMS   (NTAPS * TICKS)      // 49000 floats at ws[0]
#define P_OFF_B     196608               // byte offset of P^T[c*1000+t] (128000 floats)
#define P_ELEMS     (OUT_CH * TICKS)
#define BINS_OFF_B  708608               // byte offset of class bins
#define HOT_OFF_B   1757184              // byte offset of per-block hot slabs (BINS+1MB)
#define HOT_BINS    4000                 // 1000 ticks x 4 hot classes
#define HOT_SLAB_B  (HOT_BINS * 4)       // 16 KB per block
#define NBH_MAX     128

// x-classes: x<6 -> x exactly; x>=6 -> 6 + (x-6)%stride.  Validity of tap kx for
// class cx is (cx>=kx) && ((cx-kx)%stride==0) — exact for x<6; for x>=6, cx>=6>=kx
// always, and (x-kx) ≡ (cx-kx) (mod stride) since x ≡ cx (mod stride).
static __device__ __forceinline__ int num_classes(int stride) {
    int n = (KW - 1) + stride;
    return n > 128 ? 128 : n;
}

static __device__ __forceinline__ bool use_class(int stride, unsigned long long ws_size) {
    if (stride < 1) return false;
    long long nc = num_classes(stride);
    long long bytes = (long long)TICKS * nc * nc * 4;
    return (long long)BINS_OFF_B + bytes <= (long long)ws_size;
}

// cold-path scatter for one event (identical semantics to the r6-passing kernel)
static __device__ __forceinline__ void scatter_event_cold(
        int t, int x, int y, float v, int stride, bool cls, int nc, float* ws) {
    float* buf  = ws;
    float* bins = (float*)((char*)ws + BINS_OFF_B);
    if (cls) {
        int cx = (x < KW - 1) ? x : (KW - 1) + (x - (KW - 1)) % stride;
        int cy = (y < KH - 1) ? y : (KH - 1) + (y - (KH - 1)) % stride;
        unsafeAtomicAdd(&bins[((long long)t * nc + cx) * nc + cy], v);
    } else {
        for (int ky = 0; ky < KH; ++ky) {
            int oy = y - ky;
            if (oy < 0 || (oy % stride) != 0) continue;
            for (int kx = 0; kx < KW; ++kx) {
                int ox = x - kx;
                if (ox < 0 || (ox % stride) != 0) continue;
                unsafeAtomicAdd(&buf[(ky * KW + kx) * TICKS + t], v);
            }
        }
    }
}

__global__ void zero_kernel(float* ws, const int* __restrict__ stride_p,
                            unsigned long long ws_size) {
    int stride = *stride_p;
    long long nbins = 0;
    if (use_class(stride, ws_size)) {
        long long nc = num_classes(stride);
        nbins = (long long)TICKS * nc * nc;
    }
    float* bins = (float*)((char*)ws + BINS_OFF_B);
    long long gid = (long long)blockIdx.x * blockDim.x + threadIdx.x;
    long long gsz = (long long)gridDim.x * blockDim.x;
    for (long long i = gid; i < BUF_ELEMS; i += gsz) ws[i] = 0.0f;
    for (long long i = gid; i < nbins; i += gsz) bins[i] = 0.0f;
}

// legacy path (used when ws too small for hot slabs): 1 global atomic / event
__global__ void scatter_kernel(const int* __restrict__ ticks, const int* __restrict__ xs,
                               const int* __restrict__ ys, const float* __restrict__ vals,
                               const int* __restrict__ stride_p, float* ws,
                               unsigned long long ws_size, int n) {
    int stride = *stride_p;
    bool cls = use_class(stride, ws_size);
    int nc = num_classes(stride);
    int gid = blockIdx.x * blockDim.x + threadIdx.x;
    if (gid >= n) return;
    scatter_event_cold(ticks[gid], xs[gid], ys[gid], vals[gid], stride, cls, nc, ws);
}

// Hot path: ~91% of events (stride<=2: x>=6 && y>=6) collapse onto <=4 classes
// per tick -> per-block LDS histogram (LDS atomics), flushed non-atomically to a
// private slab; reduce_kernel sums slabs.  Global atomics only for cold ~9%.
__global__ void __launch_bounds__(256) scatter_hot(
        const int* __restrict__ ticks, const int* __restrict__ xs,
        const int* __restrict__ ys, const float* __restrict__ vals,
        const int* __restrict__ stride_p, float* ws,
        unsigned long long ws_size, int n) {
    __shared__ float lds_bins[HOT_BINS];          // [t][cls] cls=(x-6)%s*2+(y-6)%s
    int stride = *stride_p;
    bool cls = use_class(stride, ws_size);
    int nc = num_classes(stride);
    const bool hot_ok = (stride >= 1) && (stride <= 2);
    const int tid = threadIdx.x;
    for (int i = tid; i < HOT_BINS; i += 256) lds_bins[i] = 0.0f;
    __syncthreads();
    const int gsz = gridDim.x * 256;
    for (int i = blockIdx.x * 256 + tid; i < n; i += gsz) {
        int t = ticks[i];
        int x = xs[i];
        int y = ys[i];
        float v = vals[i];
        if (hot_ok && cls && x >= KW - 1 && y >= KH - 1) {
            int c4 = ((x - (KW - 1)) % stride) * 2 + ((y - (KH - 1)) % stride);
            atomicAdd(&lds_bins[t * 4 + c4], v);           // ds_add_f32
        } else {
            scatter_event_cold(t, x, y, v, stride, cls, nc, ws);
        }
    }
    __syncthreads();
    float* slab = (float*)((char*)ws + HOT_OFF_B) + (size_t)blockIdx.x * HOT_BINS;
    for (int i = tid; i < HOT_BINS; i += 256) slab[i] = lds_bins[i];  // coalesced
}

// bins[t][6+cls/2][6+cls%2] += sum_b slab[b][t*4+cls]  (non-atomic: unique owner;
// cold atomics completed in the previous dispatch)
__global__ void reduce_hot(const int* __restrict__ stride_p, float* ws,
                           unsigned long long ws_size, int nbh) {
    int stride = *stride_p;
    if (!use_class(stride, ws_size) || stride < 1 || stride > 2) return;
    int i = blockIdx.x * blockDim.x + threadIdx.x;
    if (i >= HOT_BINS) return;
    int t  = i >> 2;
    int c4 = i & 3;
    int cxr = c4 >> 1, cyr = c4 & 1;
    if (cxr >= stride || cyr >= stride) return;   // unused classes for stride 1
    const float* slab0 = (const float*)((const char*)ws + HOT_OFF_B);
    float s = 0.0f;
    for (int b = 0; b < nbh; ++b) s += slab0[(size_t)b * HOT_BINS + i];  // coalesced
    int nc = num_classes(stride);
    float* bins = (float*)((char*)ws + BINS_OFF_B);
    bins[((long long)t * nc + (KW - 1 + cxr)) * nc + (KH - 1 + cyr)] += s;
}

__global__ void combine_kernel(const int* __restrict__ stride_p, float* ws,
                               unsigned long long ws_size) {
    int stride = *stride_p;
    if (!use_class(stride, ws_size)) return;   // direct path already filled buf
    int nc = num_classes(stride);
    const float* bins = (const float*)((const char*)ws + BINS_OFF_B);
    int i = blockIdx.x * blockDim.x + threadIdx.x;
    if (i >= BUF_ELEMS) return;
    int tap = i / TICKS;
    int t   = i % TICKS;
    int ky = tap / KW, kx = tap % KW;
    float s = 0.0f;
    for (int cx = kx; cx < nc; cx += stride)
        for (int cy = ky; cy < nc; cy += stride)
            s += bins[((long long)t * nc + cx) * nc + cy];
    ws[tap * TICKS + t] = s;   // counts of 1.0f: exact, order-independent
}

// P^T[c][t] = sum_tap W[c,tap] * buf[tap, t-1]   (1-tick delay; P^T[c][0]=0)
__global__ void matmul_kernel(const float* __restrict__ W, float* ws) {
    int gid = blockIdx.x * blockDim.x + threadIdx.x;
    if (gid >= P_ELEMS) return;
    int c = gid / TICKS;
    int t = gid - c * TICKS;
    const float* buf = ws;
    float* PT = (float*)((char*)ws + P_OFF_B);
    float acc = 0.0f;
    if (t > 0) {
        const float* wrow = W + c * NTAPS;
        const float* bcol = buf + (t - 1);
        #pragma unroll
        for (int tap = 0; tap < NTAPS; ++tap)
            acc += wrow[tap] * bcol[tap * TICKS];
    }
    PT[gid] = acc;
}

// One block, thread c = neuron c.  Fully register-resident (see r6: 146->sub-77us).
// Frozen: per-tick arithmetic textually identical to the passing version.
#define SCH 50
#define SC2 (SCH / 2)
#define NCH (TICKS / SCH)

#define RUN_CHUNK(BUF, T0, PHASE)                                         \
    _Pragma("unroll")                                                     \
    for (int tt = 0; tt < SCH; ++tt) {                                    \
        float p = ((tt & 1) ? BUF[tt >> 1].y : BUF[tt >> 1].x);           \
        ssum = ssum * DECAY + p;                                          \
        float I = 350.0f + ssum;                                          \
        float q = 1.2f * (v - (-75.0f));                                  \
        q = q * (v - (-45.0f));                                           \
        v = v + (q - u + I) * DTC;                                        \
        u = u + 0.01f * (5.0f * (v - (-75.0f)) - u) * 0.001f;             \
        float spk;                                                        \
        if (v >= 50.0f) { spk = 1.0f; v = -56.0f; u = u + 130.0f; }       \
        else            { spk = 0.0f; }                                   \
        o_s[(tt + PHASE) & 3] = spk;                                      \
        o_v[(tt + PHASE) & 3] = v;                                        \
        if (((tt + PHASE) & 3) == 3) {                                    \
            const int tb = (T0) + tt - 3;  /* tb % 4 == 0: aligned */     \
            *(float4*)(out + (size_t)c * TICKS + tb) =                    \
                make_float4(o_s[0], o_s[1], o_s[2], o_s[3]);              \
            *(float4*)(out + (size_t)(OUT_CH * TICKS) + (size_t)c * TICKS + tb) = \
                make_float4(o_v[0], o_v[1], o_v[2], o_v[3]);              \
        }                                                                 \
    }

__global__ void __launch_bounds__(OUT_CH) sim_kernel(const float* __restrict__ ws_c,
                                                     float* __restrict__ out) {
    const float2* PT2 = (const float2*)((const char*)ws_c + P_OFF_B);
    const int c = threadIdx.x;
    const float DECAY = (float)(1.0 - 0.001 / 0.01);
    const float DTC   = (float)(0.001 / 150.0);
    float v = -75.0f, u = 0.0f, ssum = 0.0f;
    float o_s[4], o_v[4];
    float2 bA[SC2], bB[SC2];
    const float2* base = PT2 + (size_t)c * (TICKS / 2);

    #pragma unroll
    for (int j = 0; j < SC2; ++j) bA[j] = base[j];

    for (int kk = 0; kk < NCH / 2; ++kk) {
        const int t0 = kk * 2 * SCH;
        {
            const float2* s = base + (t0 + SCH) / 2;
            #pragma unroll
            for (int j = 0; j < SC2; ++j) bB[j] = s[j];
        }
        RUN_CHUNK(bA, t0, 0)
        if (kk + 1 < NCH / 2) {
            const float2* s = base + (t0 + 2 * SCH) / 2;
            #pragma unroll
            for (int j = 0; j < SC2; ++j) bA[j] = s[j];
        }
        RUN_CHUNK(bB, t0 + SCH, 2)
    }
}

extern "C" void kernel_launch(void* const* d_in, const int* in_sizes, int n_in,
                              void* d_out, int out_size, void* d_ws, size_t ws_size,
                              hipStream_t stream) {
    const int*   ticks   = (const int*)d_in[0];
    const int*   xs      = (const int*)d_in[1];
    const int*   ys      = (const int*)d_in[2];
    const float* vals    = (const float*)d_in[3];
    const float* W       = (const float*)d_in[4];
    const int*   stridep = (const int*)d_in[5];
    float* ws  = (float*)d_ws;
    float* out = (float*)d_out;
    int n = in_sizes[0];
    unsigned long long wsz = (unsigned long long)ws_size;

    // hot-path block count from host-known ws_size (constant per process ->
    // identical graph every call)
    int nbh = 0;
    if (ws_size >= (size_t)HOT_OFF_B + 8 * (size_t)HOT_SLAB_B) {
        size_t fit = (ws_size - HOT_OFF_B) / HOT_SLAB_B;
        nbh = fit < NBH_MAX ? (int)fit : NBH_MAX;
    }

    zero_kernel<<<1024, 256, 0, stream>>>(ws, stridep, wsz);
    if (nbh > 0) {
        scatter_hot<<<nbh, 256, 0, stream>>>(ticks, xs, ys, vals, stridep, ws, wsz, n);
        reduce_hot<<<(HOT_BINS + 255) / 256, 256, 0, stream>>>(stridep, ws, wsz, nbh);
    } else {
        scatter_kernel<<<(n + 255) / 256, 256, 0, stream>>>(ticks, xs, ys, vals,
                                                            stridep, ws, wsz, n);
    }
    combine_kernel<<<(BUF_ELEMS + 255) / 256, 256, 0, stream>>>(stridep, ws, wsz);
    matmul_kernel<<<(P_ELEMS + 255) / 256, 256, 0, stream>>>(W, ws);
    sim_kernel<<<1, OUT_CH, 0, stream>>>(ws, out);
}